// Round 3
// baseline (213.350 us; speedup 1.0000x reference)
//
#include <hip/hip_runtime.h>
#include <hip/hip_bf16.h>
#include <math.h>

typedef __bf16 bf16_t;
typedef __bf16 bf16x8 __attribute__((ext_vector_type(8)));
typedef __bf16 bf16x4 __attribute__((ext_vector_type(4)));
typedef float floatx4 __attribute__((ext_vector_type(4)));
typedef float floatx16 __attribute__((ext_vector_type(16)));
typedef unsigned int u32;
typedef u32 u32x4 __attribute__((ext_vector_type(4)));

// Problem: B=2, S=2048, H=1024, NH=16, D=64, M=B*S=4096. All I/O fp32.
// softmax scale 1/32 and log2(e) folded into Q projection epilogue:
#define QSCALE 0.045084222f  // 0.03125 * 1.4426950408889634

__device__ __forceinline__ void gload_lds16(const bf16_t* g, bf16_t* l) {
  __builtin_amdgcn_global_load_lds(
      (const __attribute__((address_space(1))) void*)(g),
      (__attribute__((address_space(3))) void*)(l), 16, 0, 0);
}

__device__ __forceinline__ float fast_exp2(float x) {
  float r;
  asm("v_exp_f32 %0, %1" : "=v"(r) : "v"(x));
  return r;
}

__device__ __forceinline__ u32 cvt_pk_bf16(float lo, float hi) {
  u32 r;
  asm("v_cvt_pk_bf16_f32 %0, %1, %2" : "=v"(r) : "v"(lo), "v"(hi));
  return r;
}

__device__ __forceinline__ floatx16 zero16() {
  floatx16 z;
#pragma unroll
  for (int i = 0; i < 16; ++i) z[i] = 0.0f;
  return z;
}

// ---------------------------------------------------------------------------
// Kernel 0: prep (merged). blocks x<2048: cast q/k/v fp32->bf16 contiguous.
// blocks x>=2048: transpose+cast wq/wk/wv [K][N] -> bf16 [N][K].
// grid (3072, 3), block 256.  [HW-verified r8/r10]
// ---------------------------------------------------------------------------
__global__ __launch_bounds__(256) void prep_k(
    const float* __restrict__ q, const float* __restrict__ k,
    const float* __restrict__ v, const float* __restrict__ wq,
    const float* __restrict__ wk, const float* __restrict__ wv,
    bf16_t* __restrict__ xb, bf16_t* __restrict__ wt) {
  const int z = blockIdx.y;
  const int t = threadIdx.x;
  if (blockIdx.x < 2048) {
    const float* src = (z == 0) ? q : (z == 1) ? k : v;
    bf16_t* dst = xb + (size_t)z * 4194304u;
    const int i = (blockIdx.x * 256 + t) * 8;
    float4 f0 = *(const float4*)(src + i);
    float4 f1 = *(const float4*)(src + i + 4);
    bf16x8 hv;
    hv[0] = (bf16_t)f0.x; hv[1] = (bf16_t)f0.y;
    hv[2] = (bf16_t)f0.z; hv[3] = (bf16_t)f0.w;
    hv[4] = (bf16_t)f1.x; hv[5] = (bf16_t)f1.y;
    hv[6] = (bf16_t)f1.z; hv[7] = (bf16_t)f1.w;
    *(bf16x8*)(dst + i) = hv;
  } else {
    __shared__ float tile[32][33];
    const int bi = blockIdx.x - 2048;
    const int bx = bi & 31, by = bi >> 5;
    const float* src = (z == 0) ? wq : (z == 1) ? wk : wv;
    bf16_t* dst = wt + (size_t)z * 1048576u;
    const int tx = t & 31, ty = t >> 5;
    const int x = bx * 32 + tx, y = by * 32 + ty;
#pragma unroll
    for (int i = 0; i < 32; i += 8)
      tile[ty + i][tx] = src[(size_t)(y + i) * 1024 + x];
    __syncthreads();
    const int x2 = by * 32 + tx, y2 = bx * 32 + ty;
#pragma unroll
    for (int i = 0; i < 32; i += 8)
      dst[(size_t)(y2 + i) * 1024 + x2] = (bf16_t)tile[tx][ty + i];
  }
}

// ---------------------------------------------------------------------------
// Kernel 1: C = Xb @ W + b, m97-style. [HW-verified r7-r10, unchanged]
// ---------------------------------------------------------------------------
__global__ __launch_bounds__(256) void qkv_gemm_k(
    const bf16_t* __restrict__ xb3, const bf16_t* __restrict__ wt3,
    const float* __restrict__ bq, const float* __restrict__ bk,
    const float* __restrict__ bv, bf16_t* __restrict__ Qh,
    bf16_t* __restrict__ Kh, bf16_t* __restrict__ Vt) {
  const int proj = blockIdx.z;
  const bf16_t* X = xb3 + (size_t)proj * 4194304u;
  const bf16_t* Wt = wt3 + (size_t)proj * 1048576u;
  const float* bias = (proj == 0) ? bq : (proj == 1) ? bk : bv;

  __shared__ __align__(16) bf16_t As[128 * 64];  // 16 KB
  __shared__ __align__(16) bf16_t Bs[128 * 64];  // 16 KB

  const int t = threadIdx.x;
  const int lane = t & 63;
  const int w = t >> 6;
  const int wm = (w >> 1) * 64;
  const int wn = (w & 1) * 64;
  const int m0 = blockIdx.x * 128;  // x = m-index (XCD grouping)
  const int n0 = blockIdx.y * 128;
  const int lm = lane & 15;
  const int lq = lane >> 4;

  int srow[4], sg[4];
#pragma unroll
  for (int c = 0; c < 4; ++c) {
    const int E = c * 2048 + t * 8;
    srow[c] = E >> 6;
    sg[c] = (((E >> 3) & 7) ^ (srow[c] & 7)) * 8;
  }

  floatx4 acc[4][4];
#pragma unroll
  for (int i = 0; i < 4; ++i)
#pragma unroll
    for (int j = 0; j < 4; ++j) acc[i][j] = (floatx4){0.f, 0.f, 0.f, 0.f};

  for (int k0 = 0; k0 < 1024; k0 += 64) {
    __syncthreads();
#pragma unroll
    for (int c = 0; c < 4; ++c) {
      const int E = c * 2048 + t * 8;
      gload_lds16(X + (size_t)(m0 + srow[c]) * 1024 + k0 + sg[c], As + E);
      gload_lds16(Wt + (size_t)(n0 + srow[c]) * 1024 + k0 + sg[c], Bs + E);
    }
    __syncthreads();

#pragma unroll
    for (int kc = 0; kc < 2; ++kc) {
      bf16x8 a[4], b[4];
#pragma unroll
      for (int i = 0; i < 4; ++i) {
        const int ch = ((kc * 4 + lq) ^ (lm & 7)) * 8;
        a[i] = *(const bf16x8*)(As + (wm + i * 16 + lm) * 64 + ch);
        b[i] = *(const bf16x8*)(Bs + (wn + i * 16 + lm) * 64 + ch);
      }
      if (proj < 2) {
#pragma unroll
        for (int i = 0; i < 4; ++i)
#pragma unroll
          for (int j = 0; j < 4; ++j)
            acc[i][j] = __builtin_amdgcn_mfma_f32_16x16x32_bf16(b[j], a[i],
                                                               acc[i][j], 0, 0, 0);
      } else {
#pragma unroll
        for (int i = 0; i < 4; ++i)
#pragma unroll
          for (int j = 0; j < 4; ++j)
            acc[i][j] = __builtin_amdgcn_mfma_f32_16x16x32_bf16(a[i], b[j],
                                                               acc[i][j], 0, 0, 0);
      }
    }
  }

  if (proj == 2) {
#pragma unroll
    for (int j = 0; j < 4; ++j) {
      const int gn = n0 + wn + j * 16 + lm;
      const float bval = bias[gn];
      const int h = gn >> 6, d = gn & 63;
#pragma unroll
      for (int i = 0; i < 4; ++i) {
        const int gm = m0 + wm + i * 16 + lq * 4;
        const int bb = gm >> 11, s0 = gm & 2047;
        bf16x4 pk;
#pragma unroll
        for (int ii = 0; ii < 4; ++ii) pk[ii] = (bf16_t)(acc[i][j][ii] + bval);
        *(bf16x4*)(Vt + (((size_t)bb * 16 + h) * 64 + d) * 2048 + s0) = pk;
      }
    }
  } else {
    bf16_t* outp = (proj == 0) ? Qh : Kh;
    const float scale = (proj == 0) ? QSCALE : 1.0f;
#pragma unroll
    for (int j = 0; j < 4; ++j) {
      const int nb = n0 + wn + j * 16 + lq * 4;
      float bs4[4];
#pragma unroll
      for (int ii = 0; ii < 4; ++ii) bs4[ii] = bias[nb + ii];
      const int h = nb >> 6, d0 = nb & 63;
#pragma unroll
      for (int i = 0; i < 4; ++i) {
        const int gm = m0 + wm + i * 16 + lm;
        const int bb = gm >> 11, s = gm & 2047;
        bf16x4 pk;
#pragma unroll
        for (int ii = 0; ii < 4; ++ii)
          pk[ii] = (bf16_t)((acc[i][j][ii] + bs4[ii]) * scale);
        *(bf16x4*)(outp + (((size_t)bb * 16 + h) * 2048 + s) * 64 + d0) = pk;
      }
    }
  }
}

// ---------------------------------------------------------------------------
// Kernel 2: flash attention, 64 q-rows per wave.
// 32x32x16 MFMAs; 4 waves x 64 q (2 groups of 32) = Q-tile 256; KV-tile 64.
// Every K-frag and V-frag ds_read feeds BOTH q-groups -> LDS read bytes per
// score halved vs r2. P in registers (cvt_pk + permlane32_swap, verified r2).
// K/V staged by direct global_load_lds with pre-swizzled source (byte-
// identical LDS image to r2's reg-staged path), double-buffered, ONE barrier
// per tile (2-phase: stage next overlaps compute of cur).
// grid (32 bh, 8 qt) = 256 blocks = 1 block/CU; launch_bounds(256,1) gives
// the allocator the full VGPR budget (est ~230 live, 1 wave/SIMD).
// MFMA floor: 32 iters x 40 MFMA x 32 cyc = 17.1 us.
// ---------------------------------------------------------------------------
__global__ __launch_bounds__(256, 1) void attn_k(
    const bf16_t* __restrict__ Qh, const bf16_t* __restrict__ Kh,
    const bf16_t* __restrict__ Vt, float* __restrict__ out) {
  __shared__ __align__(16) bf16_t Ks[2][64 * 64];  // [key][d], chunk ^= key&7
  __shared__ __align__(16) bf16_t Vs[2][64 * 64];  // [d][key], chunk ^= d&7

  const int t = threadIdx.x;
  const int lane = t & 63;
  const int w = t >> 6;
  const int lc = lane & 31;   // M/N-col within 32x32 fragment
  const int hi = lane >> 5;   // k-half selector
  const int b = blockIdx.x >> 4, h = blockIdx.x & 15;  // x = bh (XCD grouping)
  const int q0 = blockIdx.y * 256;
  const size_t bh = (size_t)b * 16 + h;
  const bf16_t* Qb = Qh + bh * (2048 * 64);
  const bf16_t* Kb = Kh + bh * (2048 * 64);
  const bf16_t* Vb = Vt + bh * (64 * 2048);

  // Q as B-operand frags: B[k = kk*16 + hi*8 + j][n = q-col lc], 2 q-groups.
  bf16x8 qf[2][4];
#pragma unroll
  for (int qg = 0; qg < 2; ++qg)
#pragma unroll
    for (int kk = 0; kk < 4; ++kk)
      qf[qg][kk] = *(const bf16x8*)(Qb +
          (size_t)(q0 + w * 64 + qg * 32 + lc) * 64 + kk * 16 + hi * 8);

  bf16x8 ones;
#pragma unroll
  for (int j = 0; j < 8; ++j) ones[j] = (bf16_t)1.0f;

  floatx16 accO[2][2], accL[2];
#pragma unroll
  for (int qg = 0; qg < 2; ++qg) {
    accO[qg][0] = zero16();
    accO[qg][1] = zero16();
    accL[qg] = zero16();
  }

  // Direct global->LDS staging; source carries the swizzle, LDS dest is
  // lane-linear (wave-uniform base + lane*16 -- HW requirement, m104).
#define STAGE(kt, buf)                                                        \
  {                                                                           \
    _Pragma("unroll") for (int cc = 0; cc < 2; ++cc) {                        \
      const int e = cc * 2048 + t * 8;                                        \
      const int r = e >> 6, gk = ((e >> 3) & 7) ^ (r & 7);                    \
      gload_lds16(Kb + (size_t)((kt) + r) * 64 + gk * 8, Ks[buf] + e);        \
      gload_lds16(Vb + (size_t)r * 2048 + (kt) + gk * 8, Vs[buf] + e);        \
    }                                                                         \
  }

  STAGE(0, 0);
  __syncthreads();  // compiler emits vmcnt(0) before s_barrier: tile 0 ready

  int cur = 0;
  for (int kt = 0; kt < 2048; kt += 64) {
    // Issue next tile's DMA first: it overlaps the entire compute phase and
    // is drained by the vmcnt(0) at the end-of-iter barrier.
    if (kt + 64 < 2048) STAGE(kt + 64, cur ^ 1);

    const bf16_t* Kc = Ks[cur];
    const bf16_t* Vc = Vs[cur];

    // S^T = K @ Q^T : A = K[key][d] from LDS (read ONCE, feeds both qg).
    floatx16 accS[2][2];
    __builtin_amdgcn_s_setprio(1);
#pragma unroll
    for (int jn = 0; jn < 2; ++jn) {
      const int krow = jn * 32 + lc;
      floatx16 z0 = zero16(), z1 = zero16();
#pragma unroll
      for (int kk = 0; kk < 4; ++kk) {
        const bf16x8 kf = *(const bf16x8*)(Kc + krow * 64 +
                                           ((kk * 2 + hi) ^ (krow & 7)) * 8);
        z0 = __builtin_amdgcn_mfma_f32_32x32x16_bf16(kf, qf[0][kk], z0, 0, 0, 0);
        z1 = __builtin_amdgcn_mfma_f32_32x32x16_bf16(kf, qf[1][kk], z1, 0, 0, 0);
      }
      accS[0][jn] = z0;
      accS[1][jn] = z1;
    }
    __builtin_amdgcn_s_setprio(0);

    // p = 2^s, pack to bf16 pairs, permlane32_swap -> PV B-frags in regs.
    // Lane holds S^T[key = jn*32 + (r&3)+8*(r>>2)+4*hi][q=lc] for r=0..15.
    // Swaps (0,2)(1,3)(4,6)(5,7) yield u32 quads in B-frag order (k=hi*8+j).
    bf16x8 pf[2][4];
#pragma unroll
    for (int qg = 0; qg < 2; ++qg)
#pragma unroll
      for (int jn = 0; jn < 2; ++jn) {
        u32 pk8[8];
#pragma unroll
        for (int p = 0; p < 8; ++p)
          pk8[p] = cvt_pk_bf16(fast_exp2(accS[qg][jn][2 * p]),
                               fast_exp2(accS[qg][jn][2 * p + 1]));
        asm volatile("v_permlane32_swap_b32 %0, %1" : "+v"(pk8[0]), "+v"(pk8[2]));
        asm volatile("v_permlane32_swap_b32 %0, %1" : "+v"(pk8[1]), "+v"(pk8[3]));
        asm volatile("v_permlane32_swap_b32 %0, %1" : "+v"(pk8[4]), "+v"(pk8[6]));
        asm volatile("v_permlane32_swap_b32 %0, %1" : "+v"(pk8[5]), "+v"(pk8[7]));
        u32x4 f0 = {pk8[0], pk8[1], pk8[2], pk8[3]};
        u32x4 f1 = {pk8[4], pk8[5], pk8[6], pk8[7]};
        pf[qg][jn * 2] = __builtin_bit_cast(bf16x8, f0);
        pf[qg][jn * 2 + 1] = __builtin_bit_cast(bf16x8, f1);
      }

    // O^T = V @ P^T : each V-frag read feeds both qg; l via ones-MFMA.
    __builtin_amdgcn_s_setprio(1);
#pragma unroll
    for (int ks = 0; ks < 4; ++ks) {
#pragma unroll
      for (int jd = 0; jd < 2; ++jd) {
        const int vrow = jd * 32 + lc;
        const bf16x8 vf = *(const bf16x8*)(Vc + vrow * 64 +
                                           ((ks * 2 + hi) ^ (vrow & 7)) * 8);
        accO[0][jd] =
            __builtin_amdgcn_mfma_f32_32x32x16_bf16(vf, pf[0][ks], accO[0][jd], 0, 0, 0);
        accO[1][jd] =
            __builtin_amdgcn_mfma_f32_32x32x16_bf16(vf, pf[1][ks], accO[1][jd], 0, 0, 0);
      }
      accL[0] = __builtin_amdgcn_mfma_f32_32x32x16_bf16(ones, pf[0][ks], accL[0], 0, 0, 0);
      accL[1] = __builtin_amdgcn_mfma_f32_32x32x16_bf16(ones, pf[1][ks], accL[1], 0, 0, 0);
    }
    __builtin_amdgcn_s_setprio(0);

    // One barrier per tile: drains this iter's STAGE (overlapped with the
    // compute above) and guarantees all waves done reading buf[cur] before
    // next iter's STAGE overwrites it.
    __syncthreads();
    cur ^= 1;
  }
#undef STAGE

  // accL rows all equal l_q for q = lc (same col as accO), per q-group.
#pragma unroll
  for (int qg = 0; qg < 2; ++qg) {
    const float inv = 1.0f / accL[qg][0];
    // out[b][s][h*64+d]; lane: s = q0+w*64+qg*32+lc, d = jd*32+g*8+hi*4+(0..3)
    const int s = q0 + w * 64 + qg * 32 + lc;
    float* op = out + ((size_t)b * 2048 + s) * 1024 + h * 64;
#pragma unroll
    for (int jd = 0; jd < 2; ++jd)
#pragma unroll
      for (int g = 0; g < 4; ++g) {
        float4 o;
        o.x = accO[qg][jd][4 * g + 0] * inv;
        o.y = accO[qg][jd][4 * g + 1] * inv;
        o.z = accO[qg][jd][4 * g + 2] * inv;
        o.w = accO[qg][jd][4 * g + 3] * inv;
        *(float4*)(op + jd * 32 + g * 8 + hi * 4) = o;
      }
  }
}

// ---------------------------------------------------------------------------
extern "C" void kernel_launch(void* const* d_in, const int* in_sizes, int n_in,
                              void* d_out, int out_size, void* d_ws, size_t ws_size,
                              hipStream_t stream) {
  (void)in_sizes; (void)n_in; (void)out_size; (void)ws_size;
  const float* q = (const float*)d_in[0];
  const float* k = (const float*)d_in[1];
  const float* v = (const float*)d_in[2];
  // d_in[3] = mask: additive per-query-row constant under softmax => no-op.
  const float* wq = (const float*)d_in[4];
  const float* bq = (const float*)d_in[5];
  const float* wk = (const float*)d_in[6];
  const float* bk = (const float*)d_in[7];
  const float* wv = (const float*)d_in[8];
  const float* bv = (const float*)d_in[9];
  float* out = (float*)d_out;

  bf16_t* ws = (bf16_t*)d_ws;
  bf16_t* Xb = ws;                   // 3 x 4M bf16 (cast q,k,v)  = 24 MB
  bf16_t* Wt = ws + 12582912u;       // 3 x 1M bf16 (transposed W) = 6 MB
  bf16_t* Qh = Wt + 3145728u;        // 4M [b][h][s][d] (pre-scaled by QSCALE)
  bf16_t* Kh = Qh + 4194304u;        // 4M [b][h][s][d]
  bf16_t* Vt = Kh + 4194304u;        // 4M [b][h][d][s]

  prep_k<<<dim3(3072, 3, 1), dim3(256, 1, 1), 0, stream>>>(
      q, k, v, wq, wk, wv, Xb, Wt);
  qkv_gemm_k<<<dim3(32, 8, 3), dim3(256, 1, 1), 0, stream>>>(
      Xb, Wt, bq, bk, bv, Qh, Kh, Vt);
  attn_k<<<dim3(32, 8, 1), dim3(256, 1, 1), 0, stream>>>(Qh, Kh, Vt, out);
}

// Round 4
// 189.957 us; speedup vs baseline: 1.1231x; 1.1231x over previous
//
#include <hip/hip_runtime.h>
#include <hip/hip_bf16.h>
#include <math.h>

typedef __bf16 bf16_t;
typedef __bf16 bf16x8 __attribute__((ext_vector_type(8)));
typedef __bf16 bf16x4 __attribute__((ext_vector_type(4)));
typedef float floatx4 __attribute__((ext_vector_type(4)));
typedef float floatx16 __attribute__((ext_vector_type(16)));
typedef unsigned int u32;
typedef u32 u32x4 __attribute__((ext_vector_type(4)));

// Problem: B=2, S=2048, H=1024, NH=16, D=64, M=B*S=4096. All I/O fp32.
// softmax scale 1/32 and log2(e) folded into Q projection epilogue:
#define QSCALE 0.045084222f  // 0.03125 * 1.4426950408889634

__device__ __forceinline__ void gload_lds16(const bf16_t* g, bf16_t* l) {
  __builtin_amdgcn_global_load_lds(
      (const __attribute__((address_space(1))) void*)(g),
      (__attribute__((address_space(3))) void*)(l), 16, 0, 0);
}

__device__ __forceinline__ float fast_exp2(float x) {
  float r;
  asm("v_exp_f32 %0, %1" : "=v"(r) : "v"(x));
  return r;
}

__device__ __forceinline__ u32 cvt_pk_bf16(float lo, float hi) {
  u32 r;
  asm("v_cvt_pk_bf16_f32 %0, %1, %2" : "=v"(r) : "v"(lo), "v"(hi));
  return r;
}

__device__ __forceinline__ floatx16 zero16() {
  floatx16 z;
#pragma unroll
  for (int i = 0; i < 16; ++i) z[i] = 0.0f;
  return z;
}

// ---------------------------------------------------------------------------
// Kernel 0: prep (merged). blocks x<2048: cast q/k/v fp32->bf16 contiguous.
// blocks x>=2048: transpose+cast wq/wk/wv [K][N] -> bf16 [N][K].
// grid (3072, 3), block 256.  [HW-verified r8/r10]
// ---------------------------------------------------------------------------
__global__ __launch_bounds__(256) void prep_k(
    const float* __restrict__ q, const float* __restrict__ k,
    const float* __restrict__ v, const float* __restrict__ wq,
    const float* __restrict__ wk, const float* __restrict__ wv,
    bf16_t* __restrict__ xb, bf16_t* __restrict__ wt) {
  const int z = blockIdx.y;
  const int t = threadIdx.x;
  if (blockIdx.x < 2048) {
    const float* src = (z == 0) ? q : (z == 1) ? k : v;
    bf16_t* dst = xb + (size_t)z * 4194304u;
    const int i = (blockIdx.x * 256 + t) * 8;
    float4 f0 = *(const float4*)(src + i);
    float4 f1 = *(const float4*)(src + i + 4);
    bf16x8 hv;
    hv[0] = (bf16_t)f0.x; hv[1] = (bf16_t)f0.y;
    hv[2] = (bf16_t)f0.z; hv[3] = (bf16_t)f0.w;
    hv[4] = (bf16_t)f1.x; hv[5] = (bf16_t)f1.y;
    hv[6] = (bf16_t)f1.z; hv[7] = (bf16_t)f1.w;
    *(bf16x8*)(dst + i) = hv;
  } else {
    __shared__ float tile[32][33];
    const int bi = blockIdx.x - 2048;
    const int bx = bi & 31, by = bi >> 5;
    const float* src = (z == 0) ? wq : (z == 1) ? wk : wv;
    bf16_t* dst = wt + (size_t)z * 1048576u;
    const int tx = t & 31, ty = t >> 5;
    const int x = bx * 32 + tx, y = by * 32 + ty;
#pragma unroll
    for (int i = 0; i < 32; i += 8)
      tile[ty + i][tx] = src[(size_t)(y + i) * 1024 + x];
    __syncthreads();
    const int x2 = by * 32 + tx, y2 = bx * 32 + ty;
#pragma unroll
    for (int i = 0; i < 32; i += 8)
      dst[(size_t)(y2 + i) * 1024 + x2] = (bf16_t)tile[tx][ty + i];
  }
}

// ---------------------------------------------------------------------------
// Kernel 1: C = Xb @ W + b, m97-style. [HW-verified r7-r10, unchanged]
// ---------------------------------------------------------------------------
__global__ __launch_bounds__(256) void qkv_gemm_k(
    const bf16_t* __restrict__ xb3, const bf16_t* __restrict__ wt3,
    const float* __restrict__ bq, const float* __restrict__ bk,
    const float* __restrict__ bv, bf16_t* __restrict__ Qh,
    bf16_t* __restrict__ Kh, bf16_t* __restrict__ Vt) {
  const int proj = blockIdx.z;
  const bf16_t* X = xb3 + (size_t)proj * 4194304u;
  const bf16_t* Wt = wt3 + (size_t)proj * 1048576u;
  const float* bias = (proj == 0) ? bq : (proj == 1) ? bk : bv;

  __shared__ __align__(16) bf16_t As[128 * 64];  // 16 KB
  __shared__ __align__(16) bf16_t Bs[128 * 64];  // 16 KB

  const int t = threadIdx.x;
  const int lane = t & 63;
  const int w = t >> 6;
  const int wm = (w >> 1) * 64;
  const int wn = (w & 1) * 64;
  const int m0 = blockIdx.x * 128;  // x = m-index (XCD grouping)
  const int n0 = blockIdx.y * 128;
  const int lm = lane & 15;
  const int lq = lane >> 4;

  int srow[4], sg[4];
#pragma unroll
  for (int c = 0; c < 4; ++c) {
    const int E = c * 2048 + t * 8;
    srow[c] = E >> 6;
    sg[c] = (((E >> 3) & 7) ^ (srow[c] & 7)) * 8;
  }

  floatx4 acc[4][4];
#pragma unroll
  for (int i = 0; i < 4; ++i)
#pragma unroll
    for (int j = 0; j < 4; ++j) acc[i][j] = (floatx4){0.f, 0.f, 0.f, 0.f};

  for (int k0 = 0; k0 < 1024; k0 += 64) {
    __syncthreads();
#pragma unroll
    for (int c = 0; c < 4; ++c) {
      const int E = c * 2048 + t * 8;
      gload_lds16(X + (size_t)(m0 + srow[c]) * 1024 + k0 + sg[c], As + E);
      gload_lds16(Wt + (size_t)(n0 + srow[c]) * 1024 + k0 + sg[c], Bs + E);
    }
    __syncthreads();

#pragma unroll
    for (int kc = 0; kc < 2; ++kc) {
      bf16x8 a[4], b[4];
#pragma unroll
      for (int i = 0; i < 4; ++i) {
        const int ch = ((kc * 4 + lq) ^ (lm & 7)) * 8;
        a[i] = *(const bf16x8*)(As + (wm + i * 16 + lm) * 64 + ch);
        b[i] = *(const bf16x8*)(Bs + (wn + i * 16 + lm) * 64 + ch);
      }
      if (proj < 2) {
#pragma unroll
        for (int i = 0; i < 4; ++i)
#pragma unroll
          for (int j = 0; j < 4; ++j)
            acc[i][j] = __builtin_amdgcn_mfma_f32_16x16x32_bf16(b[j], a[i],
                                                               acc[i][j], 0, 0, 0);
      } else {
#pragma unroll
        for (int i = 0; i < 4; ++i)
#pragma unroll
          for (int j = 0; j < 4; ++j)
            acc[i][j] = __builtin_amdgcn_mfma_f32_16x16x32_bf16(a[i], b[j],
                                                               acc[i][j], 0, 0, 0);
      }
    }
  }

  if (proj == 2) {
#pragma unroll
    for (int j = 0; j < 4; ++j) {
      const int gn = n0 + wn + j * 16 + lm;
      const float bval = bias[gn];
      const int h = gn >> 6, d = gn & 63;
#pragma unroll
      for (int i = 0; i < 4; ++i) {
        const int gm = m0 + wm + i * 16 + lq * 4;
        const int bb = gm >> 11, s0 = gm & 2047;
        bf16x4 pk;
#pragma unroll
        for (int ii = 0; ii < 4; ++ii) pk[ii] = (bf16_t)(acc[i][j][ii] + bval);
        *(bf16x4*)(Vt + (((size_t)bb * 16 + h) * 64 + d) * 2048 + s0) = pk;
      }
    }
  } else {
    bf16_t* outp = (proj == 0) ? Qh : Kh;
    const float scale = (proj == 0) ? QSCALE : 1.0f;
#pragma unroll
    for (int j = 0; j < 4; ++j) {
      const int nb = n0 + wn + j * 16 + lq * 4;
      float bs4[4];
#pragma unroll
      for (int ii = 0; ii < 4; ++ii) bs4[ii] = bias[nb + ii];
      const int h = nb >> 6, d0 = nb & 63;
#pragma unroll
      for (int i = 0; i < 4; ++i) {
        const int gm = m0 + wm + i * 16 + lm;
        const int bb = gm >> 11, s = gm & 2047;
        bf16x4 pk;
#pragma unroll
        for (int ii = 0; ii < 4; ++ii)
          pk[ii] = (bf16_t)((acc[i][j][ii] + bs4[ii]) * scale);
        *(bf16x4*)(outp + (((size_t)bb * 16 + h) * 2048 + s) * 64 + d0) = pk;
      }
    }
  }
}

// ---------------------------------------------------------------------------
// Kernel 2: flash attention, key-split for occupancy + 64 q-rows per wave.
// 8 waves/block: waves 0-3 = keys 0..1023, waves 4-7 = keys 1024..2047, over
// the SAME 256-q tile (each wave 64q = 2 q-groups sharing every K/V frag
// read -> r3's halved LDS amplification). No running max in this softmax
// (exp2 of bounded scores), so key-split partials combine by EXACT addition
// of O-numerators and l in the epilogue (LDS exchange, reusing K/V space).
// grid (32 bh, 8 qt) = 256 blocks x 8 waves = 2 waves/SIMD (fixes r3's
// 1-wave/SIMD latency exposure). Per-group KV tiles double-buffered,
// gload_lds direct staging, ONE barrier per iter, 16 iters.
// MFMA floor: 41K cyc/CU = 17 us.
// ---------------------------------------------------------------------------
__global__ __launch_bounds__(512, 2) void attn_k(
    const bf16_t* __restrict__ Qh, const bf16_t* __restrict__ Kh,
    const bf16_t* __restrict__ Vt, float* __restrict__ out) {
  // Union: [phase 1] K/V tiles 64 KB; [phase 2, after final barrier]
  // exchange buffers Xo 64 KB + Xl 2 KB. Total 66 KB static LDS.
  __shared__ __align__(16) unsigned char smem[67584];
  bf16_t* KsB = (bf16_t*)smem;             // [grp][buf][4096] bf16 = 32 KB
  bf16_t* VsB = (bf16_t*)(smem + 32768);   // [grp][buf][4096] bf16 = 32 KB
  float4* Xo = (float4*)smem;              // [16][256] = 64 KB (epilogue)
  float* Xl = (float*)(smem + 65536);      // [2][256]  =  2 KB (epilogue)

  const int t = threadIdx.x;
  const int lane = t & 63;
  const int w = t >> 6;        // 0..7
  const int grp = w >> 2;      // key-split group
  const int wq4 = w & 3;       // q-sub-tile within group
  const int tg = t & 255;      // thread id within group (4 waves)
  const int lc = lane & 31;    // M/N-col within 32x32 fragment
  const int hi = lane >> 5;    // k-half selector
  const int koff = grp * 1024; // this group's key base
  const int b = blockIdx.x >> 4, h = blockIdx.x & 15;  // x = bh (XCD grouping)
  const int q0 = blockIdx.y * 256;
  const size_t bh = (size_t)b * 16 + h;
  const bf16_t* Qb = Qh + bh * (2048 * 64);
  const bf16_t* Kb = Kh + bh * (2048 * 64);
  const bf16_t* Vb = Vt + bh * (64 * 2048);

  // Q as B-operand frags: B[k = kk*16 + hi*8 + j][n = q-col lc], 2 q-groups.
  bf16x8 qf[2][4];
#pragma unroll
  for (int qg = 0; qg < 2; ++qg)
#pragma unroll
    for (int kk = 0; kk < 4; ++kk)
      qf[qg][kk] = *(const bf16x8*)(Qb +
          (size_t)(q0 + wq4 * 64 + qg * 32 + lc) * 64 + kk * 16 + hi * 8);

  bf16x8 ones;
#pragma unroll
  for (int j = 0; j < 8; ++j) ones[j] = (bf16_t)1.0f;

  floatx16 accO[2][2], accL[2];
#pragma unroll
  for (int qg = 0; qg < 2; ++qg) {
    accO[qg][0] = zero16();
    accO[qg][1] = zero16();
    accL[qg] = zero16();
  }

  // Direct global->LDS staging; source carries the swizzle, LDS dest is
  // lane-linear (wave-uniform base + lane*16 -- HW requirement, m104).
  // Each 4-wave group stages its own 64-key tile (kt = group-local base).
#define STAGE(kt, buf)                                                        \
  {                                                                           \
    _Pragma("unroll") for (int cc = 0; cc < 2; ++cc) {                        \
      const int e = cc * 2048 + tg * 8;                                       \
      const int r = e >> 6, gk = ((e >> 3) & 7) ^ (r & 7);                    \
      gload_lds16(Kb + (size_t)(koff + (kt) + r) * 64 + gk * 8,               \
                  KsB + (grp * 2 + (buf)) * 4096 + e);                        \
      gload_lds16(Vb + (size_t)r * 2048 + koff + (kt) + gk * 8,               \
                  VsB + (grp * 2 + (buf)) * 4096 + e);                        \
    }                                                                         \
  }

  STAGE(0, 0);
  __syncthreads();  // compiler emits vmcnt(0) before s_barrier: tile 0 ready

  int cur = 0;
  for (int it = 0; it < 16; ++it) {
    // Issue next tile's DMA first: overlaps the entire compute phase, is
    // drained by the vmcnt(0) at the end-of-iter barrier.
    if (it + 1 < 16) STAGE((it + 1) * 64, cur ^ 1);

    const bf16_t* Kc = KsB + (grp * 2 + cur) * 4096;
    const bf16_t* Vc = VsB + (grp * 2 + cur) * 4096;

    // S^T = K @ Q^T : A = K[key][d] from LDS (read ONCE, feeds both qg).
    floatx16 accS[2][2];
    __builtin_amdgcn_s_setprio(1);
#pragma unroll
    for (int jn = 0; jn < 2; ++jn) {
      const int krow = jn * 32 + lc;
      floatx16 z0 = zero16(), z1 = zero16();
#pragma unroll
      for (int kk = 0; kk < 4; ++kk) {
        const bf16x8 kf = *(const bf16x8*)(Kc + krow * 64 +
                                           ((kk * 2 + hi) ^ (krow & 7)) * 8);
        z0 = __builtin_amdgcn_mfma_f32_32x32x16_bf16(kf, qf[0][kk], z0, 0, 0, 0);
        z1 = __builtin_amdgcn_mfma_f32_32x32x16_bf16(kf, qf[1][kk], z1, 0, 0, 0);
      }
      accS[0][jn] = z0;
      accS[1][jn] = z1;
    }
    __builtin_amdgcn_s_setprio(0);

    // p = 2^s, pack to bf16 pairs, permlane32_swap -> PV B-frags in regs.
    // Lane holds S^T[key = jn*32 + (r&3)+8*(r>>2)+4*hi][q=lc] for r=0..15.
    // Swaps (0,2)(1,3)(4,6)(5,7) yield u32 quads in B-frag order (k=hi*8+j).
    bf16x8 pf[2][4];
#pragma unroll
    for (int qg = 0; qg < 2; ++qg)
#pragma unroll
      for (int jn = 0; jn < 2; ++jn) {
        u32 pk8[8];
#pragma unroll
        for (int p = 0; p < 8; ++p)
          pk8[p] = cvt_pk_bf16(fast_exp2(accS[qg][jn][2 * p]),
                               fast_exp2(accS[qg][jn][2 * p + 1]));
        asm volatile("v_permlane32_swap_b32 %0, %1" : "+v"(pk8[0]), "+v"(pk8[2]));
        asm volatile("v_permlane32_swap_b32 %0, %1" : "+v"(pk8[1]), "+v"(pk8[3]));
        asm volatile("v_permlane32_swap_b32 %0, %1" : "+v"(pk8[4]), "+v"(pk8[6]));
        asm volatile("v_permlane32_swap_b32 %0, %1" : "+v"(pk8[5]), "+v"(pk8[7]));
        u32x4 f0 = {pk8[0], pk8[1], pk8[2], pk8[3]};
        u32x4 f1 = {pk8[4], pk8[5], pk8[6], pk8[7]};
        pf[qg][jn * 2] = __builtin_bit_cast(bf16x8, f0);
        pf[qg][jn * 2 + 1] = __builtin_bit_cast(bf16x8, f1);
      }

    // O^T = V @ P^T : each V-frag read feeds both qg; l via ones-MFMA.
    __builtin_amdgcn_s_setprio(1);
#pragma unroll
    for (int ks = 0; ks < 4; ++ks) {
#pragma unroll
      for (int jd = 0; jd < 2; ++jd) {
        const int vrow = jd * 32 + lc;
        const bf16x8 vf = *(const bf16x8*)(Vc + vrow * 64 +
                                           ((ks * 2 + hi) ^ (vrow & 7)) * 8);
        accO[0][jd] =
            __builtin_amdgcn_mfma_f32_32x32x16_bf16(vf, pf[0][ks], accO[0][jd], 0, 0, 0);
        accO[1][jd] =
            __builtin_amdgcn_mfma_f32_32x32x16_bf16(vf, pf[1][ks], accO[1][jd], 0, 0, 0);
      }
      accL[0] = __builtin_amdgcn_mfma_f32_32x32x16_bf16(ones, pf[0][ks], accL[0], 0, 0, 0);
      accL[1] = __builtin_amdgcn_mfma_f32_32x32x16_bf16(ones, pf[1][ks], accL[1], 0, 0, 0);
    }
    __builtin_amdgcn_s_setprio(0);

    // One barrier per iter: drains this iter's STAGE (overlapped with the
    // compute above) and guarantees all waves of this group done reading
    // buf[cur] before next iter's STAGE overwrites it.
    __syncthreads();
    cur ^= 1;
  }
#undef STAGE

  // ---- Cross-group combine: partial sums add exactly (no softmax max). ----
  // Pairing: group-0 wave wq4 <-> group-1 wave wq4, same lane. Final loop
  // barrier above ensures K/V LDS is dead -> safe to reuse as Xo/Xl.
  const int wid = wq4 * 64 + lane;  // 0..255 pair id
  if (grp == 1) {
#pragma unroll
    for (int qg = 0; qg < 2; ++qg) {
#pragma unroll
      for (int jd = 0; jd < 2; ++jd)
#pragma unroll
        for (int g = 0; g < 4; ++g) {
          float4 x;
          x.x = accO[qg][jd][4 * g + 0];
          x.y = accO[qg][jd][4 * g + 1];
          x.z = accO[qg][jd][4 * g + 2];
          x.w = accO[qg][jd][4 * g + 3];
          Xo[(qg * 8 + jd * 4 + g) * 256 + wid] = x;  // lane-consecutive: CF
        }
      Xl[qg * 256 + wid] = accL[qg][0];
    }
  }
  __syncthreads();
  if (grp == 0) {
#pragma unroll
    for (int qg = 0; qg < 2; ++qg) {
      const float inv = 1.0f / (accL[qg][0] + Xl[qg * 256 + wid]);
      // out[b][s][h*64+d]; s = q0+wq4*64+qg*32+lc, d = jd*32+g*8+hi*4+(0..3)
      const int s = q0 + wq4 * 64 + qg * 32 + lc;
      float* op = out + ((size_t)b * 2048 + s) * 1024 + h * 64;
#pragma unroll
      for (int jd = 0; jd < 2; ++jd)
#pragma unroll
        for (int g = 0; g < 4; ++g) {
          const float4 x = Xo[(qg * 8 + jd * 4 + g) * 256 + wid];
          float4 o;
          o.x = (accO[qg][jd][4 * g + 0] + x.x) * inv;
          o.y = (accO[qg][jd][4 * g + 1] + x.y) * inv;
          o.z = (accO[qg][jd][4 * g + 2] + x.z) * inv;
          o.w = (accO[qg][jd][4 * g + 3] + x.w) * inv;
          *(float4*)(op + jd * 32 + g * 8 + hi * 4) = o;
        }
    }
  }
}

// ---------------------------------------------------------------------------
extern "C" void kernel_launch(void* const* d_in, const int* in_sizes, int n_in,
                              void* d_out, int out_size, void* d_ws, size_t ws_size,
                              hipStream_t stream) {
  (void)in_sizes; (void)n_in; (void)out_size; (void)ws_size;
  const float* q = (const float*)d_in[0];
  const float* k = (const float*)d_in[1];
  const float* v = (const float*)d_in[2];
  // d_in[3] = mask: additive per-query-row constant under softmax => no-op.
  const float* wq = (const float*)d_in[4];
  const float* bq = (const float*)d_in[5];
  const float* wk = (const float*)d_in[6];
  const float* bk = (const float*)d_in[7];
  const float* wv = (const float*)d_in[8];
  const float* bv = (const float*)d_in[9];
  float* out = (float*)d_out;

  bf16_t* ws = (bf16_t*)d_ws;
  bf16_t* Xb = ws;                   // 3 x 4M bf16 (cast q,k,v)  = 24 MB
  bf16_t* Wt = ws + 12582912u;       // 3 x 1M bf16 (transposed W) = 6 MB
  bf16_t* Qh = Wt + 3145728u;        // 4M [b][h][s][d] (pre-scaled by QSCALE)
  bf16_t* Kh = Qh + 4194304u;        // 4M [b][h][s][d]
  bf16_t* Vt = Kh + 4194304u;        // 4M [b][h][d][s]

  prep_k<<<dim3(3072, 3, 1), dim3(256, 1, 1), 0, stream>>>(
      q, k, v, wq, wk, wv, Xb, Wt);
  qkv_gemm_k<<<dim3(32, 8, 3), dim3(256, 1, 1), 0, stream>>>(
      Xb, Wt, bq, bk, bv, Qh, Kh, Vt);
  attn_k<<<dim3(32, 8, 1), dim3(512, 1, 1), 0, stream>>>(Qh, Kh, Vt, out);
}

// Round 9
// 187.792 us; speedup vs baseline: 1.1361x; 1.0115x over previous
//
#include <hip/hip_runtime.h>
#include <hip/hip_bf16.h>
#include <math.h>

typedef __bf16 bf16_t;
typedef __bf16 bf16x8 __attribute__((ext_vector_type(8)));
typedef __bf16 bf16x4 __attribute__((ext_vector_type(4)));
typedef float floatx4 __attribute__((ext_vector_type(4)));
typedef float floatx16 __attribute__((ext_vector_type(16)));
typedef unsigned int u32;
typedef u32 u32x4 __attribute__((ext_vector_type(4)));

// Problem: B=2, S=2048, H=1024, NH=16, D=64, M=B*S=4096. All I/O fp32.
// softmax scale 1/32 and log2(e) folded into Q projection epilogue:
#define QSCALE 0.045084222f  // 0.03125 * 1.4426950408889634

__device__ __forceinline__ void gload_lds16(const bf16_t* g, bf16_t* l) {
  __builtin_amdgcn_global_load_lds(
      (const __attribute__((address_space(1))) void*)(g),
      (__attribute__((address_space(3))) void*)(l), 16, 0, 0);
}

__device__ __forceinline__ float fast_exp2(float x) {
  float r;
  asm("v_exp_f32 %0, %1" : "=v"(r) : "v"(x));
  return r;
}

__device__ __forceinline__ u32 cvt_pk_bf16(float lo, float hi) {
  u32 r;
  asm("v_cvt_pk_bf16_f32 %0, %1, %2" : "=v"(r) : "v"(lo), "v"(hi));
  return r;
}

__device__ __forceinline__ floatx16 zero16() {
  floatx16 z;
#pragma unroll
  for (int i = 0; i < 16; ++i) z[i] = 0.0f;
  return z;
}

// ---------------------------------------------------------------------------
// Kernel 0: prep (merged). blocks x<2048: cast q/k/v fp32->bf16 contiguous.
// blocks x>=2048: transpose+cast wq/wk/wv [K][N] -> bf16 [N][K].
// grid (3072, 3), block 256.  [HW-verified, unchanged all session]
// ---------------------------------------------------------------------------
__global__ __launch_bounds__(256) void prep_k(
    const float* __restrict__ q, const float* __restrict__ k,
    const float* __restrict__ v, const float* __restrict__ wq,
    const float* __restrict__ wk, const float* __restrict__ wv,
    bf16_t* __restrict__ xb, bf16_t* __restrict__ wt) {
  const int z = blockIdx.y;
  const int t = threadIdx.x;
  if (blockIdx.x < 2048) {
    const float* src = (z == 0) ? q : (z == 1) ? k : v;
    bf16_t* dst = xb + (size_t)z * 4194304u;
    const int i = (blockIdx.x * 256 + t) * 8;
    float4 f0 = *(const float4*)(src + i);
    float4 f1 = *(const float4*)(src + i + 4);
    bf16x8 hv;
    hv[0] = (bf16_t)f0.x; hv[1] = (bf16_t)f0.y;
    hv[2] = (bf16_t)f0.z; hv[3] = (bf16_t)f0.w;
    hv[4] = (bf16_t)f1.x; hv[5] = (bf16_t)f1.y;
    hv[6] = (bf16_t)f1.z; hv[7] = (bf16_t)f1.w;
    *(bf16x8*)(dst + i) = hv;
  } else {
    __shared__ float tile[32][33];
    const int bi = blockIdx.x - 2048;
    const int bx = bi & 31, by = bi >> 5;
    const float* src = (z == 0) ? wq : (z == 1) ? wk : wv;
    bf16_t* dst = wt + (size_t)z * 1048576u;
    const int tx = t & 31, ty = t >> 5;
    const int x = bx * 32 + tx, y = by * 32 + ty;
#pragma unroll
    for (int i = 0; i < 32; i += 8)
      tile[ty + i][tx] = src[(size_t)(y + i) * 1024 + x];
    __syncthreads();
    const int x2 = by * 32 + tx, y2 = bx * 32 + ty;
#pragma unroll
    for (int i = 0; i < 32; i += 8)
      dst[(size_t)(y2 + i) * 1024 + x2] = (bf16_t)tile[tx][ty + i];
  }
}

// ---------------------------------------------------------------------------
// Kernel 1: C = Xb @ W + b. 2-phase double-buffered staging (stage-NEXT-
// first, compute-current, ONE barrier per iter) — the one r5 change never
// tested in isolation (r5-r7 always carried the now-condemned attn reorder).
// Numerics-identical to the verified m97-style version. LDS 64 KB ->
// 2 blocks/CU. grid (32, 8, 3), block 256.
// ---------------------------------------------------------------------------
__global__ __launch_bounds__(256, 2) void qkv_gemm_k(
    const bf16_t* __restrict__ xb3, const bf16_t* __restrict__ wt3,
    const float* __restrict__ bq, const float* __restrict__ bk,
    const float* __restrict__ bv, bf16_t* __restrict__ Qh,
    bf16_t* __restrict__ Kh, bf16_t* __restrict__ Vt) {
  const int proj = blockIdx.z;
  const bf16_t* X = xb3 + (size_t)proj * 4194304u;
  const bf16_t* Wt = wt3 + (size_t)proj * 1048576u;
  const float* bias = (proj == 0) ? bq : (proj == 1) ? bk : bv;

  __shared__ __align__(16) bf16_t As[2][128 * 64];  // 32 KB
  __shared__ __align__(16) bf16_t Bs[2][128 * 64];  // 32 KB

  const int t = threadIdx.x;
  const int lane = t & 63;
  const int w = t >> 6;
  const int wm = (w >> 1) * 64;
  const int wn = (w & 1) * 64;
  const int m0 = blockIdx.x * 128;  // x = m-index (XCD grouping)
  const int n0 = blockIdx.y * 128;
  const int lm = lane & 15;
  const int lq = lane >> 4;

  int srow[4], sg[4];
#pragma unroll
  for (int c = 0; c < 4; ++c) {
    const int E = c * 2048 + t * 8;
    srow[c] = E >> 6;
    sg[c] = (((E >> 3) & 7) ^ (srow[c] & 7)) * 8;
  }

  floatx4 acc[4][4];
#pragma unroll
  for (int i = 0; i < 4; ++i)
#pragma unroll
    for (int j = 0; j < 4; ++j) acc[i][j] = (floatx4){0.f, 0.f, 0.f, 0.f};

#define GSTAGE(k0, buf)                                                       \
  {                                                                           \
    _Pragma("unroll") for (int c = 0; c < 4; ++c) {                           \
      const int E = c * 2048 + t * 8;                                         \
      gload_lds16(X + (size_t)(m0 + srow[c]) * 1024 + (k0) + sg[c],           \
                  As[buf] + E);                                               \
      gload_lds16(Wt + (size_t)(n0 + srow[c]) * 1024 + (k0) + sg[c],          \
                  Bs[buf] + E);                                               \
    }                                                                         \
  }

  GSTAGE(0, 0);
  __syncthreads();  // compiler drains vmcnt(0) before s_barrier: tile 0 ready

  int cur = 0;
  for (int k0 = 0; k0 < 1024; k0 += 64) {
    // Issue next tile's DMA first: overlaps the compute below, drained by the
    // end-of-iter barrier (no mid-iter vmcnt-0 stall).
    if (k0 < 960) GSTAGE(k0 + 64, cur ^ 1);

#pragma unroll
    for (int kc = 0; kc < 2; ++kc) {
      bf16x8 a[4], b[4];
#pragma unroll
      for (int i = 0; i < 4; ++i) {
        const int ch = ((kc * 4 + lq) ^ (lm & 7)) * 8;
        a[i] = *(const bf16x8*)(As[cur] + (wm + i * 16 + lm) * 64 + ch);
        b[i] = *(const bf16x8*)(Bs[cur] + (wn + i * 16 + lm) * 64 + ch);
      }
      if (proj < 2) {
#pragma unroll
        for (int i = 0; i < 4; ++i)
#pragma unroll
          for (int j = 0; j < 4; ++j)
            acc[i][j] = __builtin_amdgcn_mfma_f32_16x16x32_bf16(b[j], a[i],
                                                               acc[i][j], 0, 0, 0);
      } else {
#pragma unroll
        for (int i = 0; i < 4; ++i)
#pragma unroll
          for (int j = 0; j < 4; ++j)
            acc[i][j] = __builtin_amdgcn_mfma_f32_16x16x32_bf16(a[i], b[j],
                                                               acc[i][j], 0, 0, 0);
      }
    }

    // One barrier per iter: drains this iter's GSTAGE (overlapped with the
    // MFMAs above) and protects buf[cur^1] reuse.
    __syncthreads();
    cur ^= 1;
  }
#undef GSTAGE

  if (proj == 2) {
#pragma unroll
    for (int j = 0; j < 4; ++j) {
      const int gn = n0 + wn + j * 16 + lm;
      const float bval = bias[gn];
      const int h = gn >> 6, d = gn & 63;
#pragma unroll
      for (int i = 0; i < 4; ++i) {
        const int gm = m0 + wm + i * 16 + lq * 4;
        const int bb = gm >> 11, s0 = gm & 2047;
        bf16x4 pk;
#pragma unroll
        for (int ii = 0; ii < 4; ++ii) pk[ii] = (bf16_t)(acc[i][j][ii] + bval);
        *(bf16x4*)(Vt + (((size_t)bb * 16 + h) * 64 + d) * 2048 + s0) = pk;
      }
    }
  } else {
    bf16_t* outp = (proj == 0) ? Qh : Kh;
    const float scale = (proj == 0) ? QSCALE : 1.0f;
#pragma unroll
    for (int j = 0; j < 4; ++j) {
      const int nb = n0 + wn + j * 16 + lq * 4;
      float bs4[4];
#pragma unroll
      for (int ii = 0; ii < 4; ++ii) bs4[ii] = bias[nb + ii];
      const int h = nb >> 6, d0 = nb & 63;
#pragma unroll
      for (int i = 0; i < 4; ++i) {
        const int gm = m0 + wm + i * 16 + lm;
        const int bb = gm >> 11, s = gm & 2047;
        bf16x4 pk;
#pragma unroll
        for (int ii = 0; ii < 4; ++ii)
          pk[ii] = (bf16_t)((acc[i][j][ii] + bs4[ii]) * scale);
        *(bf16x4*)(outp + (((size_t)bb * 16 + h) * 2048 + s) * 64 + d0) = pk;
      }
    }
  }
}

// ---------------------------------------------------------------------------
// Kernel 2: flash attention — BYTE-EXACT restore of the r4-PASSING version.
// PITFALL (r5-r8 bisect): interleaving the inline-asm pack cluster
// (v_exp/v_cvt_pk/v_permlane32_swap) with PV MFMA halves — a source-level
// register-only reorder — corrupts results at 1e-2 scale, schedule-dependent
// (suspected unmitigated hazard/hoist around opaque asm, cf. guide rules
// 18/19). DO NOT reorder pack/PV without sched_barrier(0) fencing + A/B.
// 8 waves: grp0 keys 0..1023, grp1 keys 1024..2047; exact additive combine
// in epilogue (no softmax max). grid (32 bh, 8 qt), block 512, 16 iters.
// ---------------------------------------------------------------------------
__global__ __launch_bounds__(512, 2) void attn_k(
    const bf16_t* __restrict__ Qh, const bf16_t* __restrict__ Kh,
    const bf16_t* __restrict__ Vt, float* __restrict__ out) {
  // Union: [phase 1] K/V tiles 64 KB; [phase 2, after final barrier]
  // exchange buffers Xo 64 KB + Xl 2 KB. Total 66 KB static LDS.
  __shared__ __align__(16) unsigned char smem[67584];
  bf16_t* KsB = (bf16_t*)smem;             // [grp][buf][4096] bf16 = 32 KB
  bf16_t* VsB = (bf16_t*)(smem + 32768);   // [grp][buf][4096] bf16 = 32 KB
  float4* Xo = (float4*)smem;              // [16][256] = 64 KB (epilogue)
  float* Xl = (float*)(smem + 65536);      // [2][256]  =  2 KB (epilogue)

  const int t = threadIdx.x;
  const int lane = t & 63;
  const int w = t >> 6;        // 0..7
  const int grp = w >> 2;      // key-split group
  const int wq4 = w & 3;       // q-sub-tile within group
  const int tg = t & 255;      // thread id within group (4 waves)
  const int lc = lane & 31;    // M/N-col within 32x32 fragment
  const int hi = lane >> 5;    // k-half selector
  const int koff = grp * 1024; // this group's key base
  const int b = blockIdx.x >> 4, h = blockIdx.x & 15;  // x = bh (XCD grouping)
  const int q0 = blockIdx.y * 256;
  const size_t bh = (size_t)b * 16 + h;
  const bf16_t* Qb = Qh + bh * (2048 * 64);
  const bf16_t* Kb = Kh + bh * (2048 * 64);
  const bf16_t* Vb = Vt + bh * (64 * 2048);

  // Q as B-operand frags: B[k = kk*16 + hi*8 + j][n = q-col lc], 2 q-groups.
  bf16x8 qf[2][4];
#pragma unroll
  for (int qg = 0; qg < 2; ++qg)
#pragma unroll
    for (int kk = 0; kk < 4; ++kk)
      qf[qg][kk] = *(const bf16x8*)(Qb +
          (size_t)(q0 + wq4 * 64 + qg * 32 + lc) * 64 + kk * 16 + hi * 8);

  bf16x8 ones;
#pragma unroll
  for (int j = 0; j < 8; ++j) ones[j] = (bf16_t)1.0f;

  floatx16 accO[2][2], accL[2];
#pragma unroll
  for (int qg = 0; qg < 2; ++qg) {
    accO[qg][0] = zero16();
    accO[qg][1] = zero16();
    accL[qg] = zero16();
  }

  // Direct global->LDS staging; source carries the swizzle, LDS dest is
  // lane-linear (wave-uniform base + lane*16 -- HW requirement, m104).
  // Each 4-wave group stages its own 64-key tile (kt = group-local base).
#define STAGE(kt, buf)                                                        \
  {                                                                           \
    _Pragma("unroll") for (int cc = 0; cc < 2; ++cc) {                        \
      const int e = cc * 2048 + tg * 8;                                       \
      const int r = e >> 6, gk = ((e >> 3) & 7) ^ (r & 7);                    \
      gload_lds16(Kb + (size_t)(koff + (kt) + r) * 64 + gk * 8,               \
                  KsB + (grp * 2 + (buf)) * 4096 + e);                        \
      gload_lds16(Vb + (size_t)r * 2048 + koff + (kt) + gk * 8,               \
                  VsB + (grp * 2 + (buf)) * 4096 + e);                        \
    }                                                                         \
  }

  STAGE(0, 0);
  __syncthreads();  // compiler emits vmcnt(0) before s_barrier: tile 0 ready

  int cur = 0;
  for (int it = 0; it < 16; ++it) {
    // Issue next tile's DMA first: overlaps the entire compute phase, is
    // drained by the vmcnt(0) at the end-of-iter barrier.
    if (it + 1 < 16) STAGE((it + 1) * 64, cur ^ 1);

    const bf16_t* Kc = KsB + (grp * 2 + cur) * 4096;
    const bf16_t* Vc = VsB + (grp * 2 + cur) * 4096;

    // S^T = K @ Q^T : A = K[key][d] from LDS (read ONCE, feeds both qg).
    floatx16 accS[2][2];
    __builtin_amdgcn_s_setprio(1);
#pragma unroll
    for (int jn = 0; jn < 2; ++jn) {
      const int krow = jn * 32 + lc;
      floatx16 z0 = zero16(), z1 = zero16();
#pragma unroll
      for (int kk = 0; kk < 4; ++kk) {
        const bf16x8 kf = *(const bf16x8*)(Kc + krow * 64 +
                                           ((kk * 2 + hi) ^ (krow & 7)) * 8);
        z0 = __builtin_amdgcn_mfma_f32_32x32x16_bf16(kf, qf[0][kk], z0, 0, 0, 0);
        z1 = __builtin_amdgcn_mfma_f32_32x32x16_bf16(kf, qf[1][kk], z1, 0, 0, 0);
      }
      accS[0][jn] = z0;
      accS[1][jn] = z1;
    }
    __builtin_amdgcn_s_setprio(0);

    // p = 2^s, pack to bf16 pairs, permlane32_swap -> PV B-frags in regs.
    // Lane holds S^T[key = jn*32 + (r&3)+8*(r>>2)+4*hi][q=lc] for r=0..15.
    // Swaps (0,2)(1,3)(4,6)(5,7) yield u32 quads in B-frag order (k=hi*8+j).
    bf16x8 pf[2][4];
#pragma unroll
    for (int qg = 0; qg < 2; ++qg)
#pragma unroll
      for (int jn = 0; jn < 2; ++jn) {
        u32 pk8[8];
#pragma unroll
        for (int p = 0; p < 8; ++p)
          pk8[p] = cvt_pk_bf16(fast_exp2(accS[qg][jn][2 * p]),
                               fast_exp2(accS[qg][jn][2 * p + 1]));
        asm volatile("v_permlane32_swap_b32 %0, %1" : "+v"(pk8[0]), "+v"(pk8[2]));
        asm volatile("v_permlane32_swap_b32 %0, %1" : "+v"(pk8[1]), "+v"(pk8[3]));
        asm volatile("v_permlane32_swap_b32 %0, %1" : "+v"(pk8[4]), "+v"(pk8[6]));
        asm volatile("v_permlane32_swap_b32 %0, %1" : "+v"(pk8[5]), "+v"(pk8[7]));
        u32x4 f0 = {pk8[0], pk8[1], pk8[2], pk8[3]};
        u32x4 f1 = {pk8[4], pk8[5], pk8[6], pk8[7]};
        pf[qg][jn * 2] = __builtin_bit_cast(bf16x8, f0);
        pf[qg][jn * 2 + 1] = __builtin_bit_cast(bf16x8, f1);
      }

    // O^T = V @ P^T : each V-frag read feeds both qg; l via ones-MFMA.
    __builtin_amdgcn_s_setprio(1);
#pragma unroll
    for (int ks = 0; ks < 4; ++ks) {
#pragma unroll
      for (int jd = 0; jd < 2; ++jd) {
        const int vrow = jd * 32 + lc;
        const bf16x8 vf = *(const bf16x8*)(Vc + vrow * 64 +
                                           ((ks * 2 + hi) ^ (vrow & 7)) * 8);
        accO[0][jd] =
            __builtin_amdgcn_mfma_f32_32x32x16_bf16(vf, pf[0][ks], accO[0][jd], 0, 0, 0);
        accO[1][jd] =
            __builtin_amdgcn_mfma_f32_32x32x16_bf16(vf, pf[1][ks], accO[1][jd], 0, 0, 0);
      }
      accL[0] = __builtin_amdgcn_mfma_f32_32x32x16_bf16(ones, pf[0][ks], accL[0], 0, 0, 0);
      accL[1] = __builtin_amdgcn_mfma_f32_32x32x16_bf16(ones, pf[1][ks], accL[1], 0, 0, 0);
    }
    __builtin_amdgcn_s_setprio(0);

    // One barrier per iter: drains this iter's STAGE (overlapped with the
    // compute above) and guarantees all waves of this group done reading
    // buf[cur] before next iter's STAGE overwrites it.
    __syncthreads();
    cur ^= 1;
  }
#undef STAGE

  // ---- Cross-group combine: partial sums add exactly (no softmax max). ----
  // Pairing: group-0 wave wq4 <-> group-1 wave wq4, same lane. Final loop
  // barrier above ensures K/V LDS is dead -> safe to reuse as Xo/Xl.
  const int wid = wq4 * 64 + lane;  // 0..255 pair id
  if (grp == 1) {
#pragma unroll
    for (int qg = 0; qg < 2; ++qg) {
#pragma unroll
      for (int jd = 0; jd < 2; ++jd)
#pragma unroll
        for (int g = 0; g < 4; ++g) {
          float4 x;
          x.x = accO[qg][jd][4 * g + 0];
          x.y = accO[qg][jd][4 * g + 1];
          x.z = accO[qg][jd][4 * g + 2];
          x.w = accO[qg][jd][4 * g + 3];
          Xo[(qg * 8 + jd * 4 + g) * 256 + wid] = x;  // lane-consecutive: CF
        }
      Xl[qg * 256 + wid] = accL[qg][0];
    }
  }
  __syncthreads();
  if (grp == 0) {
#pragma unroll
    for (int qg = 0; qg < 2; ++qg) {
      const float inv = 1.0f / (accL[qg][0] + Xl[qg * 256 + wid]);
      // out[b][s][h*64+d]; s = q0+wq4*64+qg*32+lc, d = jd*32+g*8+hi*4+(0..3)
      const int s = q0 + wq4 * 64 + qg * 32 + lc;
      float* op = out + ((size_t)b * 2048 + s) * 1024 + h * 64;
#pragma unroll
      for (int jd = 0; jd < 2; ++jd)
#pragma unroll
        for (int g = 0; g < 4; ++g) {
          const float4 x = Xo[(qg * 8 + jd * 4 + g) * 256 + wid];
          float4 o;
          o.x = (accO[qg][jd][4 * g + 0] + x.x) * inv;
          o.y = (accO[qg][jd][4 * g + 1] + x.y) * inv;
          o.z = (accO[qg][jd][4 * g + 2] + x.z) * inv;
          o.w = (accO[qg][jd][4 * g + 3] + x.w) * inv;
          *(float4*)(op + jd * 32 + g * 8 + hi * 4) = o;
        }
    }
  }
}

// ---------------------------------------------------------------------------
extern "C" void kernel_launch(void* const* d_in, const int* in_sizes, int n_in,
                              void* d_out, int out_size, void* d_ws, size_t ws_size,
                              hipStream_t stream) {
  (void)in_sizes; (void)n_in; (void)out_size; (void)ws_size;
  const float* q = (const float*)d_in[0];
  const float* k = (const float*)d_in[1];
  const float* v = (const float*)d_in[2];
  // d_in[3] = mask: additive per-query-row constant under softmax => no-op.
  const float* wq = (const float*)d_in[4];
  const float* bq = (const float*)d_in[5];
  const float* wk = (const float*)d_in[6];
  const float* bk = (const float*)d_in[7];
  const float* wv = (const float*)d_in[8];
  const float* bv = (const float*)d_in[9];
  float* out = (float*)d_out;

  bf16_t* ws = (bf16_t*)d_ws;
  bf16_t* Xb = ws;                   // 3 x 4M bf16 (cast q,k,v)  = 24 MB
  bf16_t* Wt = ws + 12582912u;       // 3 x 1M bf16 (transposed W) = 6 MB
  bf16_t* Qh = Wt + 3145728u;        // 4M [b][h][s][d] (pre-scaled by QSCALE)
  bf16_t* Kh = Qh + 4194304u;        // 4M [b][h][s][d]
  bf16_t* Vt = Kh + 4194304u;        // 4M [b][h][d][s]

  prep_k<<<dim3(3072, 3, 1), dim3(256, 1, 1), 0, stream>>>(
      q, k, v, wq, wk, wv, Xb, Wt);
  qkv_gemm_k<<<dim3(32, 8, 3), dim3(256, 1, 1), 0, stream>>>(
      Xb, Wt, bq, bk, bv, Qh, Kh, Vt);
  attn_k<<<dim3(32, 8, 1), dim3(512, 1, 1), 0, stream>>>(Qh, Kh, Vt, out);
}